// Round 1
// baseline (9954.746 us; speedup 1.0000x reference)
//
#include <hip/hip_runtime.h>

#define NS    4096
#define DDIM  100
#define HD    110
#define HP    112
#define TSTEPS 50
#define DTc   0.02f
#define EPSc  1e-6f

// ---------------- weight transpose (+pad to 112 cols) ----------------
__global__ void kw_prep(const float* __restrict__ w1, const float* __restrict__ w2,
                        const float* __restrict__ w3,
                        float* __restrict__ wt1, float* __restrict__ wt2,
                        float* __restrict__ wt3) {
  int tid = threadIdx.x;
  for (int i = tid; i < DDIM * HP; i += blockDim.x) {
    int k = i / HP, j = i % HP;
    wt1[i] = (j < HD) ? w1[j * DDIM + k] : 0.f;   // w1 [110,100] -> wt1[k<100][j<112]
  }
  for (int i = tid; i < HD * HP; i += blockDim.x) {
    int k = i / HP, j = i % HP;
    wt2[i] = (j < HD) ? w2[j * HD + k] : 0.f;     // w2 [110,110] -> wt2[k<110][j]
    wt3[i] = (j < DDIM) ? w3[j * HD + k] : 0.f;   // w3 [100,110] -> wt3[k<110][j<100]
  }
}

// ---------------- dw transpose: dwT[t][d][n] = dw[n][d][t] ----------------
__global__ __launch_bounds__(256) void kt_dw(const float* __restrict__ dw,
                                             float* __restrict__ dwT) {
  int n = blockIdx.x * 256 + threadIdx.x;
  int d = blockIdx.y;
  const float2* src = (const float2*)(dw + (size_t)n * DDIM * TSTEPS + d * TSTEPS);
  float v[TSTEPS];
#pragma unroll
  for (int i = 0; i < TSTEPS / 2; ++i) {
    float2 p = src[i];
    v[2 * i] = p.x; v[2 * i + 1] = p.y;
  }
#pragma unroll
  for (int t = 0; t < TSTEPS; ++t)
    dwT[((size_t)t * DDIM + d) * NS + n] = v[t];   // coalesced over n
}

// ---------------- per-step state update (x,y,u,z) + bn0 stats ----------------
__global__ __launch_bounds__(256) void ka_step(
    int t, int flags,  // bit0 first, bit1 final, bit2 use dwT
    const float* __restrict__ dw, const float* __restrict__ dwT,
    const float* __restrict__ y_init, const float* __restrict__ z_init,
    const float* __restrict__ bn3w, const float* __restrict__ bn3b,
    float* __restrict__ x, float* __restrict__ y, const float* __restrict__ h3,
    const float* __restrict__ stats3, float* __restrict__ stats0,
    float* __restrict__ stats2_zero, float* __restrict__ lacc,
    float* __restrict__ out_y, float* __restrict__ out_ye,
    float* __restrict__ out_xs, float* __restrict__ out_us)
{
  const bool first  = flags & 1;
  const bool last_  = flags & 2;
  const bool usedwt = flags & 4;
  int tid = threadIdx.x;
  int n = blockIdx.x * 256 + tid;
  int wave = tid >> 6, lane = tid & 63;

  __shared__ float2 zp[DDIM];        // z = h3*A + B  (bn3 folded, /1e4)
  __shared__ float2 part[4][DDIM];   // per-wave (sum, sumsq) partials for x_new
  __shared__ float red2[8];

  if (blockIdx.x == 0 && tid < 224) stats2_zero[tid] = 0.f;  // zero stats2 for K_C(t)

  if (!first && tid < DDIM) {
    float m = stats3[tid] * (1.f / NS);
    float v = stats3[HP + tid] * (1.f / NS) - m * m;
    float istd = rsqrtf(v + EPSc);
    float A = istd * bn3w[tid] * 1e-4f;                  // /(DIM*DIM)
    float B = (bn3b[tid] - m * istd * bn3w[tid]) * 1e-4f;
    zp[tid] = make_float2(A, B);
  }
  __syncthreads();

  float sz = 0.f, szdw = 0.f, sumx2 = 0.f;
  for (int d = 0; d < DDIM; ++d) {
    float zd  = first ? z_init[d] : fmaf(h3[d * NS + n], zp[d].x, zp[d].y);
    float dwv = usedwt ? dwT[((size_t)t * DDIM + d) * NS + n]
                       : dw[(size_t)n * DDIM * TSTEPS + d * TSTEPS + t];
    float xv  = first ? 0.f : x[d * NS + n];
    sz += zd;
    szdw  = fmaf(zd, dwv, szdw);
    sumx2 = fmaf(xv, xv, sumx2);
  }
  float u = fminf(fmaxf(-sz, -1.f), 1.f);
  float yv = first ? y_init[0] : y[n];
  yv += -DTc * 0.5f * (sumx2 + u * u) + DTc * sz * u + szdw;
  out_us[t * NS + n] = u;

  if (!last_) {
    y[n] = yv;
    for (int d = 0; d < DDIM; ++d) {
      float xv  = first ? 0.f : x[d * NS + n];
      float dwv = usedwt ? dwT[((size_t)t * DDIM + d) * NS + n]
                         : dw[(size_t)n * DDIM * TSTEPS + d * TSTEPS + t];
      float xn = fmaf(xv, 1.f - DTc, fmaf(u, DTc, dwv));
      x[d * NS + n] = xn;
      out_xs[((size_t)t * NS + n) * DDIM + d] = xv;      // ENTRY x
      float s = xn, q = xn * xn;
      for (int off = 32; off; off >>= 1) {
        s += __shfl_down(s, off);
        q += __shfl_down(q, off);
      }
      if (lane == 0) part[wave][d] = make_float2(s, q);
    }
    __syncthreads();
    if (tid < DDIM) {
      float s = part[0][tid].x + part[1][tid].x + part[2][tid].x + part[3][tid].x;
      atomicAdd(&stats0[tid], s);
    } else if (tid < 2 * DDIM) {
      int d2 = tid - DDIM;
      float q = part[0][d2].y + part[1][d2].y + part[2][d2].y + part[3][d2].y;
      atomicAdd(&stats0[HP + d2], q);
    }
  } else {
    out_y[n] = yv;
    float ye = 0.5f * sumx2;
    out_ye[n] = ye;
    for (int d = 0; d < DDIM; ++d)
      out_xs[((size_t)t * NS + n) * DDIM + d] = x[d * NS + n];
    float dd = yv - ye;
    float ad = fabsf(dd);
    float sl1 = ad < 1.f ? 0.5f * dd * dd : ad - 0.5f;
    float s = sl1, q = ye;
    for (int off = 32; off; off >>= 1) {
      s += __shfl_down(s, off);
      q += __shfl_down(q, off);
    }
    if (lane == 0) { red2[wave] = s; red2[4 + wave] = q; }
    __syncthreads();
    if (tid == 0) {
      atomicAdd(&lacc[0], red2[0] + red2[1] + red2[2] + red2[3]);
      atomicAdd(&lacc[1], red2[4] + red2[5] + red2[6] + red2[7]);
    }
  }
}

// ---------------- generic fused bn(+relu) -> matmul -> stats ----------------
// out[j][n] = sum_k act(bn(in[k][n])) * wt[k][j] (+bias[j]); accumulate per-j stats.
template <int KD, int RELU>
__global__ __launch_bounds__(256) void km_layer(
    const float* __restrict__ in, float* __restrict__ out,
    const float* __restrict__ stats_in, float* __restrict__ stats_out,
    float* __restrict__ zero_ptr,
    const float* __restrict__ bnw, const float* __restrict__ bnb,
    const float* __restrict__ wt, const float* __restrict__ bias, int Jreal)
{
  int tid = threadIdx.x;
  int lane = tid & 63;
  int j0 = blockIdx.y * 28 + (tid >> 6) * 7;
  int n = blockIdx.x * 64 + lane;

  __shared__ float2 ab[HP];
  if (tid < KD) {
    float m = stats_in[tid] * (1.f / NS);
    float v = stats_in[HP + tid] * (1.f / NS) - m * m;
    float istd = rsqrtf(v + EPSc);
    float A = istd * bnw[tid];
    float B = bnb[tid] - m * A;
    ab[tid] = make_float2(A, B);
  }
  if (blockIdx.x == 0 && blockIdx.y == 0 && tid < 224) zero_ptr[tid] = 0.f;
  __syncthreads();

  j0 = __builtin_amdgcn_readfirstlane(j0);   // force SGPR -> s_load of weights

  float acc[7] = {0, 0, 0, 0, 0, 0, 0};
#pragma unroll 2
  for (int k = 0; k < KD; ++k) {
    float a = in[k * NS + n];
    float2 p = ab[k];
    a = fmaf(a, p.x, p.y);
    if (RELU) a = fmaxf(a, 0.f);
    const float* wr = wt + k * HP + j0;
#pragma unroll
    for (int jj = 0; jj < 7; ++jj)
      acc[jj] = fmaf(a, wr[jj], acc[jj]);
  }

#pragma unroll
  for (int jj = 0; jj < 7; ++jj) {
    int j = j0 + jj;
    if (j < Jreal) {
      float vv = acc[jj] + (bias ? bias[j] : 0.f);
      out[j * NS + n] = vv;
      float s = vv, q = vv * vv;
      for (int off = 32; off; off >>= 1) {
        s += __shfl_down(s, off);
        q += __shfl_down(q, off);
      }
      if (lane == 0) {
        atomicAdd(&stats_out[j], s);
        atomicAdd(&stats_out[HP + j], q);
      }
    }
  }
}

__global__ void k_loss(const float* __restrict__ lacc, float* __restrict__ out_loss) {
  float sl1 = lacc[0] * (1.f / NS);
  float mye = lacc[1] * (1.f / NS);
  out_loss[0] = 100.f * (sl1 + mye * mye);   // 2*DELTA_CLIP = 100
}

extern "C" void kernel_launch(void* const* d_in, const int* in_sizes, int n_in,
                              void* d_out, int out_size, void* d_ws, size_t ws_size,
                              hipStream_t stream) {
  const float* dw     = (const float*)d_in[0];
  const float* y_init = (const float*)d_in[1];
  const float* z_init = (const float*)d_in[2];
  const float* bn0w   = (const float*)d_in[3];
  const float* bn0b   = (const float*)d_in[4];
  const float* w1     = (const float*)d_in[5];
  const float* bn1w   = (const float*)d_in[6];
  const float* bn1b   = (const float*)d_in[7];
  const float* w2     = (const float*)d_in[8];
  const float* bn2w   = (const float*)d_in[9];
  const float* bn2b   = (const float*)d_in[10];
  const float* w3     = (const float*)d_in[11];
  const float* b3     = (const float*)d_in[12];
  const float* bn3w   = (const float*)d_in[13];
  const float* bn3b   = (const float*)d_in[14];

  float* ws  = (float*)d_ws;
  float* x   = ws;                       // [100][4096]
  float* y   = x + 409600;               // [4096]
  float* h1  = y + 4096;                 // [112][4096]
  float* h2  = h1 + (size_t)HP * NS;
  float* h3  = h2 + (size_t)HP * NS;
  float* st  = h3 + (size_t)HP * NS;     // 4 x 224
  float* st0 = st, *st1 = st + 224, *st2 = st + 448, *st3 = st + 672;
  float* lacc = st + 896;                // 2 (+pad)
  float* wt1 = lacc + 8;                 // [100][112]
  float* wt2 = wt1 + DDIM * HP;          // [110][112]
  float* wt3 = wt2 + HD * HP;            // [110][112]
  float* dwT = wt3 + HD * HP;            // [50][100][4096] (optional)
  size_t need_dwt = ((size_t)(dwT - ws) + (size_t)TSTEPS * DDIM * NS) * sizeof(float);
  bool usedwt = ws_size >= need_dwt;

  float* out      = (float*)d_out;
  float* out_loss = out;
  float* out_y    = out + 1;
  float* out_ye   = out_y + NS;
  float* out_xs   = out_ye + NS;
  float* out_us   = out_xs + (size_t)TSTEPS * NS * DDIM;

  hipMemsetAsync(st, 0, (896 + 8) * sizeof(float), stream);
  kw_prep<<<1, 256, 0, stream>>>(w1, w2, w3, wt1, wt2, wt3);
  if (usedwt) kt_dw<<<dim3(16, 100), 256, 0, stream>>>(dw, dwT);

  for (int t = 0; t < TSTEPS; ++t) {
    int flags = (t == 0 ? 1 : 0) | (t == TSTEPS - 1 ? 2 : 0) | (usedwt ? 4 : 0);
    ka_step<<<16, 256, 0, stream>>>(t, flags, dw, dwT, y_init, z_init,
                                    bn3w, bn3b, x, y, h3, st3, st0, st2, lacc,
                                    out_y, out_ye, out_xs, out_us);
    if (t < TSTEPS - 1) {
      km_layer<100, 0><<<dim3(64, 4), 256, 0, stream>>>(
          x, h1, st0, st1, st3, bn0w, bn0b, wt1, (const float*)nullptr, HD);
      km_layer<110, 1><<<dim3(64, 4), 256, 0, stream>>>(
          h1, h2, st1, st2, st0, bn1w, bn1b, wt2, (const float*)nullptr, HD);
      km_layer<110, 1><<<dim3(64, 4), 256, 0, stream>>>(
          h2, h3, st2, st3, st1, bn2w, bn2b, wt3, b3, DDIM);
    }
  }
  k_loss<<<1, 1, 0, stream>>>(lacc, out_loss);
}

// Round 3
// 5627.613 us; speedup vs baseline: 1.7689x; 1.7689x over previous
//
#include <hip/hip_runtime.h>

#define NS    4096
#define DDIM  100
#define HD    110
#define HP    112
#define TSTEPS 50
#define DTc   0.02f
#define EPSc  1e-6f

// ---------------- weight prep: per-j-tile transposed [jt][k][8] ----------------
__global__ void kw_prep(const float* __restrict__ w1, const float* __restrict__ w2,
                        const float* __restrict__ w3,
                        float* __restrict__ wtt1, float* __restrict__ wtt2,
                        float* __restrict__ wtt3) {
  int tid = threadIdx.x;
  for (int idx = tid; idx < 14 * 100 * 8; idx += 256) {
    int jt = idx / 800, r = idx % 800, k = r / 8, jj = r % 8, j = jt * 8 + jj;
    wtt1[idx] = (j < HD) ? w1[j * DDIM + k] : 0.f;     // w1 [110,100]
  }
  for (int idx = tid; idx < 14 * 110 * 8; idx += 256) {
    int jt = idx / 880, r = idx % 880, k = r / 8, jj = r % 8, j = jt * 8 + jj;
    wtt2[idx] = (j < HD) ? w2[j * HD + k] : 0.f;       // w2 [110,110]
  }
  for (int idx = tid; idx < 13 * 110 * 8; idx += 256) {
    int jt = idx / 880, r = idx % 880, k = r / 8, jj = r % 8, j = jt * 8 + jj;
    wtt3[idx] = (j < DDIM) ? w3[j * HD + k] : 0.f;     // w3 [100,110]
  }
}

// ---------------- dw transpose: dwT[t][d][n] = dw[n][d][t] ----------------
__global__ __launch_bounds__(256) void kt_dw(const float* __restrict__ dw,
                                             float* __restrict__ dwT) {
  int n = blockIdx.x * 256 + threadIdx.x;
  int d = blockIdx.y;
  const float2* src = (const float2*)(dw + (size_t)n * DDIM * TSTEPS + d * TSTEPS);
  float v[TSTEPS];
#pragma unroll
  for (int i = 0; i < TSTEPS / 2; ++i) {
    float2 p = src[i];
    v[2 * i] = p.x; v[2 * i + 1] = p.y;
  }
#pragma unroll
  for (int t = 0; t < TSTEPS; ++t)
    dwT[((size_t)t * DDIM + d) * NS + n] = v[t];
}

// ---------------- per-step state update: grid 64, block 1024 (16 waves) ------
// wave w owns d in [7w, 7w+7) (clamped to 100); lane = n within block's 64-n tile.
__global__ __launch_bounds__(1024) void ka2(
    int t, int flags,  // bit0 first, bit1 last, bit2 use dwT
    const float* __restrict__ dw, const float* __restrict__ dwT,
    const float* __restrict__ y_init, const float* __restrict__ z_init,
    const float* __restrict__ bn3w, const float* __restrict__ bn3b,
    float* __restrict__ x, float* __restrict__ y, const float* __restrict__ h3,
    const float* __restrict__ stats3, float* __restrict__ stats0,
    float* __restrict__ st_zero, float* __restrict__ lacc,
    float* __restrict__ out_y, float* __restrict__ out_ye,
    float* __restrict__ out_xs, float* __restrict__ out_us)
{
  const bool first  = flags & 1;
  const bool last_  = flags & 2;
  const bool usedwt = flags & 4;
  int tid = threadIdx.x, lane = tid & 63, w = tid >> 6;
  int n = blockIdx.x * 64 + lane;
  int d0 = w * 7;
  int nd = DDIM - d0; nd = nd < 0 ? 0 : (nd > 7 ? 7 : nd);

  __shared__ float2 zp[DDIM];
  __shared__ float ps[3][16][64];
  __shared__ float ush[64];
  __shared__ float pst[2][112];

  if (blockIdx.x == 0 && tid < 224) st_zero[tid] = 0.f;
  if (!first && tid < DDIM) {
    float m = stats3[tid] * (1.f / NS);
    float v = stats3[HP + tid] * (1.f / NS) - m * m;
    float istd = rsqrtf(v + EPSc);
    float A = istd * bn3w[tid] * 1e-4f;
    float B = (bn3b[tid] - m * istd * bn3w[tid]) * 1e-4f;
    zp[tid] = make_float2(A, B);
  }
  __syncthreads();

  float xv[7], dwv[7];
  float pz = 0.f, pzdw = 0.f, px2 = 0.f;
#pragma unroll
  for (int i = 0; i < 7; ++i) {
    if (i < nd) {
      int d = d0 + i;
      float zd = first ? z_init[d] : fmaf(h3[d * NS + n], zp[d].x, zp[d].y);
      dwv[i] = usedwt ? dwT[((size_t)t * DDIM + d) * NS + n]
                      : dw[(size_t)n * DDIM * TSTEPS + d * TSTEPS + t];
      xv[i] = first ? 0.f : x[d * NS + n];
      pz += zd;
      pzdw = fmaf(zd, dwv[i], pzdw);
      px2 = fmaf(xv[i], xv[i], px2);
    }
  }
  ps[0][w][lane] = pz; ps[1][w][lane] = pzdw; ps[2][w][lane] = px2;
  __syncthreads();

  if (w == 0) {
    float sz = 0.f, szdw = 0.f, sx2 = 0.f;
#pragma unroll
    for (int k = 0; k < 16; ++k) {
      sz += ps[0][k][lane]; szdw += ps[1][k][lane]; sx2 += ps[2][k][lane];
    }
    float u = fminf(fmaxf(-sz, -1.f), 1.f);
    float yv = first ? y_init[0] : y[n];
    yv += -DTc * 0.5f * (sx2 + u * u) + DTc * sz * u + szdw;
    out_us[t * NS + n] = u;
    ush[lane] = u;
    if (!last_) {
      y[n] = yv;
    } else {
      out_y[n] = yv;
      float ye = 0.5f * sx2;
      out_ye[n] = ye;
      float dd = yv - ye, ad = fabsf(dd);
      float s = ad < 1.f ? 0.5f * dd * dd : ad - 0.5f;
      float q = ye;
      for (int off = 32; off; off >>= 1) {
        s += __shfl_down(s, off);
        q += __shfl_down(q, off);
      }
      if (lane == 0) { atomicAdd(&lacc[0], s); atomicAdd(&lacc[1], q); }
    }
  }
  __syncthreads();

  if (!last_) {
    float u = ush[lane];
#pragma unroll
    for (int i = 0; i < 7; ++i) {
      if (i < nd) {
        int d = d0 + i;
        float xn = fmaf(xv[i], 1.f - DTc, fmaf(u, DTc, dwv[i]));
        x[d * NS + n] = xn;
        out_xs[((size_t)t * NS + n) * DDIM + d] = xv[i];
        float s = xn, q = xn * xn;
        for (int off = 32; off; off >>= 1) {
          s += __shfl_down(s, off);
          q += __shfl_down(q, off);
        }
        if (lane == 0) { pst[0][d] = s; pst[1][d] = q; }
      }
    }
    __syncthreads();
    if (tid < DDIM) atomicAdd(&stats0[tid], pst[0][tid]);
    else if (tid >= 128 && tid < 128 + DDIM) atomicAdd(&stats0[HP + tid - 128], pst[1][tid - 128]);
  } else {
#pragma unroll
    for (int i = 0; i < 7; ++i)
      if (i < nd)
        out_xs[((size_t)t * NS + n) * DDIM + i + d0] = xv[i];
  }
}

// ---------------- fused bn(+relu) -> matmul -> stats; 1-wave blocks ----------
// grid (64 n-tiles, JT j-tiles of 8). Weights broadcast from LDS.
template <int KD, int RELU, int HASB>
__global__ __launch_bounds__(64) void km2(
    const float* __restrict__ in, float* __restrict__ out,
    const float* __restrict__ stats_in, float* __restrict__ stats_out,
    float* __restrict__ zero_ptr,
    const float* __restrict__ bnw, const float* __restrict__ bnb,
    const float* __restrict__ wtt, const float* __restrict__ bias, int Jreal)
{
  int tid = threadIdx.x;
  int jt = blockIdx.y;
  int n = blockIdx.x * 64 + tid;

  __shared__ float4 wl[KD * 2];
  __shared__ float2 ab[KD];

  const float4* src = (const float4*)(wtt + (size_t)jt * KD * 8);
  for (int i = tid; i < KD * 2; i += 64) wl[i] = src[i];
  for (int k = tid; k < KD; k += 64) {
    float m = stats_in[k] * (1.f / NS);
    float v = stats_in[HP + k] * (1.f / NS) - m * m;
    float istd = rsqrtf(v + EPSc);
    float A = istd * bnw[k];
    ab[k] = make_float2(A, bnb[k] - m * A);
  }
  if (blockIdx.x == 0 && jt == 0)
    for (int i = tid; i < 224; i += 64) zero_ptr[i] = 0.f;
  __syncthreads();

  float acc[8] = {0, 0, 0, 0, 0, 0, 0, 0};
  const float* ip = in + n;
#pragma unroll 10
  for (int k = 0; k < KD; ++k) {
    float a = ip[(size_t)k * NS];
    float2 p = ab[k];
    a = fmaf(a, p.x, p.y);
    if (RELU) a = fmaxf(a, 0.f);
    float4 wA = wl[2 * k], wB = wl[2 * k + 1];
    acc[0] = fmaf(a, wA.x, acc[0]); acc[1] = fmaf(a, wA.y, acc[1]);
    acc[2] = fmaf(a, wA.z, acc[2]); acc[3] = fmaf(a, wA.w, acc[3]);
    acc[4] = fmaf(a, wB.x, acc[4]); acc[5] = fmaf(a, wB.y, acc[5]);
    acc[6] = fmaf(a, wB.z, acc[6]); acc[7] = fmaf(a, wB.w, acc[7]);
  }

  int j0 = jt * 8;
#pragma unroll
  for (int jj = 0; jj < 8; ++jj) {
    int j = j0 + jj;
    if (j < Jreal) {
      float vv = acc[jj] + (HASB ? bias[j] : 0.f);
      out[j * NS + n] = vv;
      float s = vv, q = vv * vv;
      for (int off = 32; off; off >>= 1) {
        s += __shfl_down(s, off);
        q += __shfl_down(q, off);
      }
      if (tid == 0) {
        atomicAdd(&stats_out[j], s);
        atomicAdd(&stats_out[HP + j], q);
      }
    }
  }
}

__global__ void k_loss(const float* __restrict__ lacc, float* __restrict__ out_loss) {
  float sl1 = lacc[0] * (1.f / NS);
  float mye = lacc[1] * (1.f / NS);
  out_loss[0] = 100.f * (sl1 + mye * mye);   // 2*DELTA_CLIP = 100
}

extern "C" void kernel_launch(void* const* d_in, const int* in_sizes, int n_in,
                              void* d_out, int out_size, void* d_ws, size_t ws_size,
                              hipStream_t stream) {
  const float* dw     = (const float*)d_in[0];
  const float* y_init = (const float*)d_in[1];
  const float* z_init = (const float*)d_in[2];
  const float* bn0w   = (const float*)d_in[3];
  const float* bn0b   = (const float*)d_in[4];
  const float* w1     = (const float*)d_in[5];
  const float* bn1w   = (const float*)d_in[6];
  const float* bn1b   = (const float*)d_in[7];
  const float* w2     = (const float*)d_in[8];
  const float* bn2w   = (const float*)d_in[9];
  const float* bn2b   = (const float*)d_in[10];
  const float* w3     = (const float*)d_in[11];
  const float* b3     = (const float*)d_in[12];
  const float* bn3w   = (const float*)d_in[13];
  const float* bn3b   = (const float*)d_in[14];

  float* ws  = (float*)d_ws;
  float* x   = ws;                        // [100][4096]
  float* y   = x + 409600;                // [4096]
  float* h1  = y + 4096;                  // [112][4096]
  float* h2  = h1 + (size_t)HP * NS;
  float* h3  = h2 + (size_t)HP * NS;
  float* st  = h3 + (size_t)HP * NS;      // 4 x 224 stats + loss acc
  float* st0 = st, *st1 = st + 224, *st2 = st + 448, *st3 = st + 672;
  float* lacc = st + 896;
  float* wtt1 = lacc + 8;                 // [14][100][8]
  float* wtt2 = wtt1 + 14 * 100 * 8;      // [14][110][8]
  float* wtt3 = wtt2 + 14 * 110 * 8;      // [13][110][8]
  float* dwT  = wtt3 + 13 * 110 * 8;      // [50][100][4096] (optional)
  size_t need_dwt = ((size_t)(dwT - ws) + (size_t)TSTEPS * DDIM * NS) * sizeof(float);
  bool usedwt = ws_size >= need_dwt;

  float* out      = (float*)d_out;
  float* out_loss = out;
  float* out_y    = out + 1;
  float* out_ye   = out_y + NS;
  float* out_xs   = out_ye + NS;
  float* out_us   = out_xs + (size_t)TSTEPS * NS * DDIM;

  hipMemsetAsync(st, 0, (896 + 8) * sizeof(float), stream);
  kw_prep<<<1, 256, 0, stream>>>(w1, w2, w3, wtt1, wtt2, wtt3);
  if (usedwt) kt_dw<<<dim3(16, 100), 256, 0, stream>>>(dw, dwT);

  for (int t = 0; t < TSTEPS; ++t) {
    int flags = (t == 0 ? 1 : 0) | (t == TSTEPS - 1 ? 2 : 0) | (usedwt ? 4 : 0);
    ka2<<<64, 1024, 0, stream>>>(t, flags, dw, dwT, y_init, z_init,
                                 bn3w, bn3b, x, y, h3, st3, st0, st2, lacc,
                                 out_y, out_ye, out_xs, out_us);
    if (t < TSTEPS - 1) {
      km2<100, 0, 0><<<dim3(64, 14), 64, 0, stream>>>(
          x, h1, st0, st1, st3, bn0w, bn0b, wtt1, (const float*)nullptr, HD);
      km2<110, 1, 0><<<dim3(64, 14), 64, 0, stream>>>(
          h1, h2, st1, st2, st0, bn1w, bn1b, wtt2, (const float*)nullptr, HD);
      km2<110, 1, 1><<<dim3(64, 13), 64, 0, stream>>>(
          h2, h3, st2, st3, st1, bn2w, bn2b, wtt3, b3, DDIM);
    }
  }
  k_loss<<<1, 1, 0, stream>>>(lacc, out_loss);
}